// Round 20
// baseline (3156.286 us; speedup 1.0000x reference)
//
#include <hip/hip_runtime.h>
#include <math.h>

#define B_SZ   4096
#define T_SZ   60
#define F_SZ   30
#define H_ENC  256
#define HD_DEC 100
#define LATD   256
#define KM     352   // MFMA K: [x 0..73 | pad 74,75 | h 76..331 | pad ..351]
#define KMP    360   // padded row stride (45*16B, odd -> conflict-free b128 reads)
#define NKK    11    // 352/32
#define DEC_IN 279
#define DTAIL  24    // dlq 9 + mp 14 + pad 1

// ---------------- workspace layout (float offsets) ----------------
enum {
  OFF_PWM_F = 0,                            // 11*64 frags * 64 lanes * 8 bf16 = 180224 u32
  OFF_PWM_B = OFF_PWM_F + 180224,
  OFF_BEN_F = OFF_PWM_B + 180224,           // [1024] bias in n'=4u+g order
  OFF_BEN_B = OFF_BEN_F + 1024,
  OFF_PLAT  = OFF_BEN_B + 1024,             // 256*256 float2 {mu,lv}
  OFF_P1I   = OFF_PLAT + 256*256*2,         // 280*100 float4
  OFF_P1H   = OFF_P1I + 280*100*4,
  OFF_P2I   = OFF_P1H + 100*100*4,
  OFF_P2H   = OFF_P2I + 100*100*4,
  OFF_WG1T  = OFF_P2H + 100*100*4,          // [100][25]
  OFF_BE1   = OFF_WG1T + 100*25,            // [400]
  OFF_BE2   = OFF_BE1 + 400,
  OFF_HF    = OFF_BE2 + 400,                // [4096][256]
  OFF_HB    = OFF_HF + B_SZ*H_ENC,
  OFF_Z     = OFF_HB + B_SZ*H_ENC,
  OFF_H1    = OFF_Z + B_SZ*LATD,
  OFF_C1    = OFF_H1 + B_SZ*HD_DEC,
  OFF_H2    = OFF_C1 + B_SZ*HD_DEC,
  OFF_C2    = OFF_H2 + B_SZ*HD_DEC,
  OFF_DLQ   = OFF_C2 + B_SZ*HD_DEC,
  OFF_XBUF  = OFF_DLQ + B_SZ*9,
  OFF_MU    = OFF_XBUF + B_SZ*25,
  OFF_RSTD  = OFF_MU + 25,
  OFF_ZW1   = OFF_RSTD + 25,                // [4096][400]
  WS_FLOATS = OFF_ZW1 + B_SZ*400
};

typedef __attribute__((ext_vector_type(8))) short short8v;
typedef __attribute__((ext_vector_type(4))) float f32x4;

__device__ __forceinline__ float sigf(float x) { return 1.0f / (1.0f + expf(-x)); }

__device__ __forceinline__ unsigned short f2bf(float f) {
  union { float f; unsigned int u; } v; v.f = f;
  unsigned int u = v.u + 0x7fffu + ((v.u >> 16) & 1u);
  return (unsigned short)(u >> 16);
}
__device__ __forceinline__ float bf2f(unsigned short s) {
  union { unsigned int u; float f; } v; v.u = ((unsigned int)s) << 16;
  return v.f;
}

// ---------------- prep ----------------
// mode 0 pack f4:  dst[(k*U+u)*G+g] = k<C ? a[(g*U+u)*C+k] : 0   (U=p0,C=p1,Kp=p2,G=p3)
// mode 1 bias sum: dst[i] = a[i]+b[i], i<p0
// mode 4 MFMA B-frag pack (validated r18): frag f = kk*64+ntg; lane l;
//   8 bf16: B[k=32kk+8(l>>4)+j][n'=16ntg+(l&15)], W(k,n'): u=n'>>2,g=n'&3
// mode 5 bias n'-order: dst[4u+g] = a[g*256+u] + b[g*256+u]
struct PJob { const float* a; const float* b; float* dst; int p0, p1, p2, p3, mode; };
struct PrepArgs { PJob j[12]; };

__device__ __forceinline__ float enc_wv(const float* wih, const float* whh, int k, int u, int g) {
  if (k < 74)  return wih[(g * 256 + u) * 74 + k];
  if (k < 76)  return 0.0f;
  if (k < 332) return whh[(g * 256 + u) * 256 + (k - 76)];
  return 0.0f;
}

__global__ __launch_bounds__(256) void prep_kernel(PrepArgs pa) {
  int gtid = blockIdx.x * blockDim.x + threadIdx.x;
  int stride = gridDim.x * blockDim.x;
  for (int jj = 0; jj < 12; ++jj) {
    PJob jb = pa.j[jj];
    if (jb.mode == 1) {
      for (int i = gtid; i < jb.p0; i += stride) jb.dst[i] = jb.a[i] + jb.b[i];
    } else if (jb.mode == 0) {
      int total = jb.p2 * jb.p0;
      for (int i = gtid; i < total; i += stride) {
        int k = i / jb.p0, u = i - k * jb.p0;
        float* d = jb.dst + (size_t)i * jb.p3;
        for (int g = 0; g < jb.p3; ++g)
          d[g] = (k < jb.p1) ? jb.a[(g * jb.p0 + u) * jb.p1 + k] : 0.0f;
      }
    } else if (jb.mode == 4) {
      int total = NKK * 64 * 64;
      for (int i = gtid; i < total; i += stride) {
        int kk = i / 4096, rem = i - kk * 4096;
        int ntg = rem >> 6, l = rem & 63;
        int n = ntg * 16 + (l & 15);
        int u = n >> 2, g = n & 3;
        int kb = kk * 32 + (l >> 4) * 8;
        unsigned int* d = (unsigned int*)jb.dst + (size_t)i * 4;
        for (int wd = 0; wd < 4; ++wd) {
          float lo = enc_wv(jb.a, jb.b, kb + 2 * wd,     u, g);
          float hi = enc_wv(jb.a, jb.b, kb + 2 * wd + 1, u, g);
          d[wd] = (unsigned int)f2bf(lo) | ((unsigned int)f2bf(hi) << 16);
        }
      }
    } else { // mode 5
      for (int i = gtid; i < 1024; i += stride) {
        int u = i >> 2, g = i & 3;
        jb.dst[i] = jb.a[g * 256 + u] + jb.b[g * 256 + u];
      }
    }
  }
}

#define GDOT(acc, c, w0, w1, w2, w3, xv) \
  acc = fmaf((w0).c, (xv).x, fmaf((w1).c, (xv).y, fmaf((w2).c, (xv).z, fmaf((w3).c, (xv).w, acc))))

// ---------------- encoder: MFMA bf16, M=32 rows/block ----------------
// 256 blocks; bwd = blockIdx.x & 1, c = blockIdx.x >> 1: with XCD = id % 8,
// even XCDs host ONLY fwd blocks, odd ONLY bwd -> per-XCD weight working set
// halves to 720 KB (r19 FETCH 3.95 GB = L2 misses on a set that should be
// resident). seq/ymd staging uses NON-TEMPORAL loads so the 58 MB stream
// doesn't evict weight lines from L2.
// 512 threads = 8 waves; wave w owns n' in [128w,128w+128). Two A row-tiles
// share every B fragment. V rows padded to KMP=360. mfma layouts validated r18.
__global__ __launch_bounds__(512) void enc_kernel(
    const float* __restrict__ seq, const int* __restrict__ seq_len,
    const int* __restrict__ ymd, const int* __restrict__ acq,
    const float* __restrict__ Ea0, const float* __restrict__ Ea1, const float* __restrict__ Ea2,
    const float* __restrict__ Es0, const float* __restrict__ Es1, const float* __restrict__ Es2,
    const unsigned short* __restrict__ PWMf, const unsigned short* __restrict__ PWMb,
    const float* __restrict__ benF, const float* __restrict__ benB,
    float* __restrict__ hf_out, float* __restrict__ hb_out)
{
  const int tid = threadIdx.x;
  const bool bwd = (blockIdx.x & 1) != 0;   // direction by parity -> XCD locality
  const int c = blockIdx.x >> 1;
  const unsigned short* __restrict__ PWM = bwd ? PWMb : PWMf;
  const float* __restrict__ ben = bwd ? benB : benF;
  float* __restrict__ hout = bwd ? hb_out : hf_out;

  __shared__ __align__(16) unsigned short v_s[32][KMP];  // bf16: x|pad|h|pad
  __shared__ float c_s[32][256];
  __shared__ int   len_s[32];

  for (int i = tid; i < 32 * KMP; i += 512) (&v_s[0][0])[i] = 0;
  for (int i = tid; i < 32 * 256; i += 512) (&c_s[0][0])[i] = 0.0f;
  if (tid < 32) len_s[tid] = seq_len[c + 128 * tid];
  __syncthreads();

  // acquisition embeds (t-invariant): V[30..57]
  for (int i = tid; i < 32 * 28; i += 512) {
    int r = i / 28, d = i - r * 28;
    const int* aq = &acq[(c + 128 * r) * 3];
    float v;
    if (d < 16)      v = Ea0[aq[0] * 16 + d];
    else if (d < 24) v = Ea1[aq[1] * 8 + (d - 16)];
    else             v = Ea2[aq[2] * 4 + (d - 24)];
    v_s[r][30 + d] = f2bf(v);
  }

  const int w   = tid >> 6;           // wave 0..7
  const int l   = tid & 63;
  const int col = l & 15;
  const int qk  = l >> 4;
  const int g   = l & 3;
  const int usub = col >> 2;

  float bias_r[8];
  #pragma unroll
  for (int nt = 0; nt < 8; ++nt) bias_r[nt] = ben[128 * w + 16 * nt + col];

  __syncthreads();
  const int maxlen = len_s[0];        // rows ranked desc in j

  for (int t = 0; t < maxlen; ++t) {
    // ---- stage x(t): seq 960 + ey 512 = 1472 items (non-temporal reads) ----
    for (int i = tid; i < 1472; i += 512) {
      if (i < 960) {
        int r = i / 30, k = i - r * 30;
        int len = len_s[r];
        int te = bwd ? max(len - 1 - t, 0) : t;
        float sv = __builtin_nontemporal_load(
            &seq[((size_t)(c + 128 * r) * T_SZ + te) * F_SZ + k]);
        v_s[r][k] = f2bf(sv);
      } else {
        int ii = i - 960;
        int r = ii >> 4, d = ii & 15;
        int len = len_s[r];
        int te = bwd ? max(len - 1 - t, 0) : t;
        const int* ym = &ymd[((size_t)(c + 128 * r) * T_SZ + te) * 3];
        int y0, idx;
        float v;
        if (d < 8)       { y0 = __builtin_nontemporal_load(&ym[0]); v = Es0[y0 * 8 + d]; }
        else if (d < 12) { y0 = __builtin_nontemporal_load(&ym[1]); v = Es1[y0 * 4 + (d - 8)]; }
        else             { y0 = __builtin_nontemporal_load(&ym[2]); v = Es2[y0 * 4 + (d - 12)]; }
        (void)idx;
        v_s[r][58 + d] = f2bf(v);
      }
    }
    __syncthreads();                  // A: V(x t, h t-1) ready

    f32x4 acc0[8], acc1[8];
    #pragma unroll
    for (int nt = 0; nt < 8; ++nt) {
      acc0[nt][0] = bias_r[nt]; acc0[nt][1] = bias_r[nt];
      acc0[nt][2] = bias_r[nt]; acc0[nt][3] = bias_r[nt];
      acc1[nt] = acc0[nt];
    }

    for (int kk = 0; kk < NKK; ++kk) {
      short8v a0 = *reinterpret_cast<const short8v*>(&v_s[col][32 * kk + 8 * qk]);
      short8v a1 = *reinterpret_cast<const short8v*>(&v_s[16 + col][32 * kk + 8 * qk]);
      const unsigned short* Bk = PWM + ((size_t)kk * 4096 + l) * 8;
      #pragma unroll
      for (int nt = 0; nt < 8; ++nt) {
        int ntg = 8 * w + nt;
        short8v b = *reinterpret_cast<const short8v*>(Bk + (size_t)ntg * 512);
        acc0[nt] = __builtin_amdgcn_mfma_f32_16x16x32_bf16(a0, b, acc0[nt], 0, 0, 0);
        acc1[nt] = __builtin_amdgcn_mfma_f32_16x16x32_bf16(a1, b, acc1[nt], 0, 0, 0);
      }
    }
    __syncthreads();                  // B: all V reads of step t done

    // ---- cell update: gates of unit u in lanes {l|g=0..3} of a row-quad ----
    #pragma unroll
    for (int rt = 0; rt < 2; ++rt) {
      #pragma unroll
      for (int nt = 0; nt < 8; ++nt) {
        int u = 32 * w + 4 * nt + usub;
        #pragma unroll
        for (int i = 0; i < 4; ++i) {
          int row = 16 * rt + qk * 4 + i;
          float val = rt == 0 ? acc0[nt][i] : acc1[nt][i];
          float act = (g == 2) ? tanhf(val) : sigf(val);
          float a1s = __shfl_xor(act, 1);
          float a2s = __shfl_xor(act, 2);
          float a3s = __shfl_xor(a1s, 2);
          if (g == 0 && t < len_s[row]) {
            float cc = c_s[row][u];
            float cn = a1s * cc + act * a2s;   // sig(f)*c + sig(i)*tanh(g)
            c_s[row][u] = cn;
            v_s[row][76 + u] = f2bf(a3s * tanhf(cn));  // sig(o)*tanh(c)
          }
        }
      }
    }
    // next iteration's barrier A publishes h(t)
  }

  __syncthreads();
  for (int i = tid; i < 32 * 256; i += 512) {
    int r = i >> 8, u = i & 255;
    hout[(size_t)(c + 128 * r) * H_ENC + u] = bf2f(v_s[r][76 + u]);
  }
}

// ---------------- latent ----------------
__global__ __launch_bounds__(256) void latent_kernel(
    const float* __restrict__ hf, const float* __restrict__ hb,
    const float2* __restrict__ Plat, const float* __restrict__ b_lat,
    const float* __restrict__ z_noise, const float* __restrict__ seq,
    const int* __restrict__ seq_len,
    float* __restrict__ z, float* __restrict__ dlq,
    float* __restrict__ h1w, float* __restrict__ c1w,
    float* __restrict__ h2w, float* __restrict__ c2w)
{
  const int tid = threadIdx.x;
  const int b0 = blockIdx.x * 16;
  __shared__ float hs[16][H_ENC];
  for (int i = tid; i < 16 * H_ENC; i += 256)
    (&hs[0][0])[i] = hf[b0 * H_ENC + i] + hb[b0 * H_ENC + i];
  __syncthreads();

  const int u = tid;
  const float bm = b_lat[u], bv = b_lat[LATD + u];
  float am[16], av[16];
  #pragma unroll
  for (int r = 0; r < 16; ++r) { am[r] = bm; av[r] = bv; }

  for (int k = 0; k < H_ENC; k += 4) {
    const float2 p0 = Plat[(k + 0) * 256 + u];
    const float2 p1 = Plat[(k + 1) * 256 + u];
    const float2 p2 = Plat[(k + 2) * 256 + u];
    const float2 p3 = Plat[(k + 3) * 256 + u];
    #pragma unroll
    for (int r = 0; r < 16; ++r) {
      const float4 hv = *reinterpret_cast<const float4*>(&hs[r][k]);
      am[r] = fmaf(p0.x, hv.x, fmaf(p1.x, hv.y, fmaf(p2.x, hv.z, fmaf(p3.x, hv.w, am[r]))));
      av[r] = fmaf(p0.y, hv.x, fmaf(p1.y, hv.y, fmaf(p2.y, hv.z, fmaf(p3.y, hv.w, av[r]))));
    }
  }
  #pragma unroll
  for (int r = 0; r < 16; ++r) {
    int b = b0 + r;
    z[b * LATD + u] = am[r] + sqrtf(expf(av[r])) * z_noise[b * LATD + u];
  }
  if (u < HD_DEC) {
    #pragma unroll
    for (int r = 0; r < 16; ++r) {
      int b = b0 + r;
      h1w[b * HD_DEC + u] = 0.0f; c1w[b * HD_DEC + u] = 0.0f;
      h2w[b * HD_DEC + u] = 0.0f; c2w[b * HD_DEC + u] = 0.0f;
    }
  }
  if (u < 9) {
    #pragma unroll
    for (int r = 0; r < 16; ++r) {
      int b = b0 + r;
      int len = seq_len[b];
      dlq[b * 9 + u] = seq[(b * T_SZ + (len - 1)) * F_SZ + 21 + u];
    }
  }
}

// ---------------- decoder z-precompute ----------------
__global__ __launch_bounds__(256) void dec_zpre_kernel(
    const float* __restrict__ z, const float4* __restrict__ P1I,
    float* __restrict__ zw1)
{
  const int tid = threadIdx.x;
  const int b0 = blockIdx.x * 16;
  __shared__ float zs[16][LATD];
  for (int i = tid; i < 16 * LATD; i += 256)
    (&zs[0][0])[i] = z[b0 * LATD + i];
  __syncthreads();

  const int u = tid & 127;
  const int grp = tid >> 7;
  const int r0 = grp * 8;
  if (u >= HD_DEC) return;

  float a0[8], a1[8], a2[8], a3[8];
  #pragma unroll
  for (int r = 0; r < 8; ++r) { a0[r] = 0.0f; a1[r] = 0.0f; a2[r] = 0.0f; a3[r] = 0.0f; }
  for (int k = 0; k < LATD; k += 4) {
    const float4 w0 = P1I[(k + 0) * 100 + u];
    const float4 w1 = P1I[(k + 1) * 100 + u];
    const float4 w2 = P1I[(k + 2) * 100 + u];
    const float4 w3 = P1I[(k + 3) * 100 + u];
    #pragma unroll
    for (int r = 0; r < 8; ++r) {
      const float4 xv = *reinterpret_cast<const float4*>(&zs[r0 + r][k]);
      GDOT(a0[r], x, w0, w1, w2, w3, xv);
      GDOT(a1[r], y, w0, w1, w2, w3, xv);
      GDOT(a2[r], z, w0, w1, w2, w3, xv);
      GDOT(a3[r], w, w0, w1, w2, w3, xv);
    }
  }
  #pragma unroll
  for (int r = 0; r < 8; ++r) {
    int b = b0 + r0 + r;
    zw1[b * 400 + u]       = a0[r];
    zw1[b * 400 + 100 + u] = a1[r];
    zw1[b * 400 + 200 + u] = a2[r];
    zw1[b * 400 + 300 + u] = a3[r];
  }
}

// ---------------- decoder cell step ----------------
__global__ __launch_bounds__(256) void dec_cell_kernel(
    const float* __restrict__ zw1, const float* __restrict__ dlq,
    const float* __restrict__ macro,
    float* __restrict__ h1w, float* __restrict__ c1w,
    float* __restrict__ h2w, float* __restrict__ c2w,
    const float4* __restrict__ P1I, const float4* __restrict__ P1H, const float* __restrict__ be1,
    const float4* __restrict__ P2I, const float4* __restrict__ P2H, const float* __restrict__ be2,
    const float* __restrict__ Wg1T, const float* __restrict__ bg1,
    float* __restrict__ xbuf, int t)
{
  const int tid = threadIdx.x;
  const int b0 = blockIdx.x * 16;
  __shared__ float di[16][DTAIL];
  __shared__ float h1s[16][HD_DEC];
  __shared__ float h2s[16][HD_DEC];

  for (int i = tid; i < 16 * DTAIL; i += 256) {
    int r = i / DTAIL, k = i - r * DTAIL;
    int b = b0 + r;
    float v;
    if (k < 9)       v = dlq[b * 9 + k];
    else if (k < 23) v = macro[(b * 12 + t) * 14 + (k - 9)];
    else             v = 0.0f;
    di[r][k] = v;
  }
  for (int i = tid; i < 16 * HD_DEC; i += 256) {
    int r = i / HD_DEC, k = i - r * HD_DEC;
    h1s[r][k] = h1w[(b0 + r) * HD_DEC + k];
    h2s[r][k] = h2w[(b0 + r) * HD_DEC + k];
  }

  const int u = tid & 127;
  const int grp = tid >> 7;
  const int r0 = grp * 8;
  const bool act = u < HD_DEC;

  float c1r[8], c2r[8];
  if (act) {
    #pragma unroll
    for (int r = 0; r < 8; ++r) {
      c1r[r] = c1w[(b0 + r0 + r) * HD_DEC + u];
      c2r[r] = c2w[(b0 + r0 + r) * HD_DEC + u];
    }
  }
  __syncthreads();

  float a0[8], a1[8], a2[8], a3[8];
  if (act) {
    const float b0g = be1[u], b1g = be1[100 + u], b2g = be1[200 + u], b3g = be1[300 + u];
    #pragma unroll
    for (int r = 0; r < 8; ++r) {
      const float* zw = &zw1[(size_t)(b0 + r0 + r) * 400];
      a0[r] = b0g + zw[u];
      a1[r] = b1g + zw[100 + u];
      a2[r] = b2g + zw[200 + u];
      a3[r] = b3g + zw[300 + u];
    }
    for (int k = 0; k < DTAIL; k += 4) {
      const int kk = LATD + k;
      const float4 w0 = P1I[(kk + 0) * 100 + u];
      const float4 w1 = P1I[(kk + 1) * 100 + u];
      const float4 w2 = P1I[(kk + 2) * 100 + u];
      const float4 w3 = P1I[(kk + 3) * 100 + u];
      #pragma unroll
      for (int r = 0; r < 8; ++r) {
        const float4 xv = *reinterpret_cast<const float4*>(&di[r0 + r][k]);
        GDOT(a0[r], x, w0, w1, w2, w3, xv);
        GDOT(a1[r], y, w0, w1, w2, w3, xv);
        GDOT(a2[r], z, w0, w1, w2, w3, xv);
        GDOT(a3[r], w, w0, w1, w2, w3, xv);
      }
    }
    for (int k = 0; k < HD_DEC; k += 4) {
      const float4 w0 = P1H[(k + 0) * 100 + u];
      const float4 w1 = P1H[(k + 1) * 100 + u];
      const float4 w2 = P1H[(k + 2) * 100 + u];
      const float4 w3 = P1H[(k + 3) * 100 + u];
      #pragma unroll
      for (int r = 0; r < 8; ++r) {
        const float4 hv = *reinterpret_cast<const float4*>(&h1s[r0 + r][k]);
        GDOT(a0[r], x, w0, w1, w2, w3, hv);
        GDOT(a1[r], y, w0, w1, w2, w3, hv);
        GDOT(a2[r], z, w0, w1, w2, w3, hv);
        GDOT(a3[r], w, w0, w1, w2, w3, hv);
      }
    }
  }
  __syncthreads();
  if (act) {
    #pragma unroll
    for (int r = 0; r < 8; ++r) {
      float ig = sigf(a0[r]), fg = sigf(a1[r]), gg = tanhf(a2[r]), og = sigf(a3[r]);
      float cn = fg * c1r[r] + ig * gg;
      float hn = og * tanhf(cn);
      int b = b0 + r0 + r;
      h1s[r0 + r][u] = hn;
      h1w[b * HD_DEC + u] = hn;
      c1w[b * HD_DEC + u] = cn;
    }
  }
  __syncthreads();

  if (act) {
    const float b0g = be2[u], b1g = be2[100 + u], b2g = be2[200 + u], b3g = be2[300 + u];
    #pragma unroll
    for (int r = 0; r < 8; ++r) { a0[r] = b0g; a1[r] = b1g; a2[r] = b2g; a3[r] = b3g; }
    for (int k = 0; k < HD_DEC; k += 4) {
      const float4 w0 = P2I[(k + 0) * 100 + u];
      const float4 w1 = P2I[(k + 1) * 100 + u];
      const float4 w2 = P2I[(k + 2) * 100 + u];
      const float4 w3 = P2I[(k + 3) * 100 + u];
      #pragma unroll
      for (int r = 0; r < 8; ++r) {
        const float4 hv = *reinterpret_cast<const float4*>(&h1s[r0 + r][k]);
        GDOT(a0[r], x, w0, w1, w2, w3, hv);
        GDOT(a1[r], y, w0, w1, w2, w3, hv);
        GDOT(a2[r], z, w0, w1, w2, w3, hv);
        GDOT(a3[r], w, w0, w1, w2, w3, hv);
      }
    }
    for (int k = 0; k < HD_DEC; k += 4) {
      const float4 w0 = P2H[(k + 0) * 100 + u];
      const float4 w1 = P2H[(k + 1) * 100 + u];
      const float4 w2 = P2H[(k + 2) * 100 + u];
      const float4 w3 = P2H[(k + 3) * 100 + u];
      #pragma unroll
      for (int r = 0; r < 8; ++r) {
        const float4 hv = *reinterpret_cast<const float4*>(&h2s[r0 + r][k]);
        GDOT(a0[r], x, w0, w1, w2, w3, hv);
        GDOT(a1[r], y, w0, w1, w2, w3, hv);
        GDOT(a2[r], z, w0, w1, w2, w3, hv);
        GDOT(a3[r], w, w0, w1, w2, w3, hv);
      }
    }
  }
  __syncthreads();
  if (act) {
    #pragma unroll
    for (int r = 0; r < 8; ++r) {
      float ig = sigf(a0[r]), fg = sigf(a1[r]), gg = tanhf(a2[r]), og = sigf(a3[r]);
      float cn = fg * c2r[r] + ig * gg;
      float hn = og * tanhf(cn);
      int b = b0 + r0 + r;
      h2s[r0 + r][u] = hn;
      h2w[b * HD_DEC + u] = hn;
      c2w[b * HD_DEC + u] = cn;
    }
  }
  __syncthreads();

  for (int p = tid; p < 16 * 25; p += 256) {
    int r = p / 25, cc = p - r * 25;
    float s = bg1[cc];
    for (int k = 0; k < HD_DEC; k += 4) {
      const float4 hv = *reinterpret_cast<const float4*>(&h2s[r][k]);
      s += hv.x * Wg1T[k * 25 + cc] + hv.y * Wg1T[(k + 1) * 25 + cc]
         + hv.z * Wg1T[(k + 2) * 25 + cc] + hv.w * Wg1T[(k + 3) * 25 + cc];
    }
    xbuf[(b0 + r) * 25 + cc] = fmaxf(s, 0.0f);
  }
}

// ---------------- decoder batchnorm stats ----------------
__global__ __launch_bounds__(256) void dec_stats_kernel(
    const float* __restrict__ xbuf, float* __restrict__ muv, float* __restrict__ rstdv)
{
  const int col = blockIdx.x;
  const int tid = threadIdx.x;
  __shared__ float red[256];
  float v[16];
  float s = 0.0f;
  #pragma unroll
  for (int i = 0; i < 16; ++i) { v[i] = xbuf[(tid + 256 * i) * 25 + col]; s += v[i]; }
  red[tid] = s; __syncthreads();
  for (int off = 128; off >= 1; off >>= 1) {
    if (tid < off) red[tid] += red[tid + off];
    __syncthreads();
  }
  float mean = red[0] / (float)B_SZ;
  __syncthreads();
  float s2 = 0.0f;
  #pragma unroll
  for (int i = 0; i < 16; ++i) { float d = v[i] - mean; s2 += d * d; }
  red[tid] = s2; __syncthreads();
  for (int off = 128; off >= 1; off >>= 1) {
    if (tid < off) red[tid] += red[tid + off];
    __syncthreads();
  }
  if (tid == 0) {
    muv[col] = mean;
    rstdv[col] = rsqrtf(red[0] / (float)B_SZ + 1e-5f);
  }
}

// ---------------- decoder normalize + output ----------------
__global__ __launch_bounds__(256) void dec_out_kernel(
    const float* __restrict__ xbuf, const float* __restrict__ muv, const float* __restrict__ rstdv,
    const float* __restrict__ gamma, const float* __restrict__ beta,
    const float* __restrict__ Wg2, const float* __restrict__ bg2,
    float* __restrict__ dlq, float* __restrict__ out, int t)
{
  int b = blockIdx.x * 256 + threadIdx.x;
  float xn[25];
  #pragma unroll
  for (int c = 0; c < 25; ++c)
    xn[c] = gamma[c] * (xbuf[b * 25 + c] - muv[c]) * rstdv[c] + beta[c];
  #pragma unroll
  for (int j = 0; j < 9; ++j) {
    float s = bg2[j];
    #pragma unroll
    for (int c = 0; c < 25; ++c) s += xn[c] * Wg2[j * 25 + c];
    dlq[b * 9 + j] = s;
    out[b * 108 + j * 12 + t] = s;
  }
}

// ---------------- host launch ----------------
extern "C" void kernel_launch(void* const* d_in, const int* in_sizes, int n_in,
                              void* d_out, int out_size, void* d_ws, size_t ws_size,
                              hipStream_t stream)
{
  const float* seq     = (const float*)d_in[0];
  const int*   seq_len = (const int*)  d_in[1];
  const int*   ymd     = (const int*)  d_in[2];
  const int*   acq     = (const int*)  d_in[3];
  const float* macro   = (const float*)d_in[4];
  const float* z_noise = (const float*)d_in[5];
  const float* Ea0 = (const float*)d_in[6];
  const float* Ea1 = (const float*)d_in[7];
  const float* Ea2 = (const float*)d_in[8];
  const float* Es0 = (const float*)d_in[9];
  const float* Es1 = (const float*)d_in[10];
  const float* Es2 = (const float*)d_in[11];
  const float* Wih_f = (const float*)d_in[12];
  const float* Whh_f = (const float*)d_in[13];
  const float* bih_f = (const float*)d_in[14];
  const float* bhh_f = (const float*)d_in[15];
  const float* Wih_b = (const float*)d_in[16];
  const float* Whh_b = (const float*)d_in[17];
  const float* bih_b = (const float*)d_in[18];
  const float* bhh_b = (const float*)d_in[19];
  const float* W_lat = (const float*)d_in[20];
  const float* b_lat = (const float*)d_in[21];
  const float* Wih1  = (const float*)d_in[22];
  const float* Whh1  = (const float*)d_in[23];
  const float* bih1  = (const float*)d_in[24];
  const float* bhh1  = (const float*)d_in[25];
  const float* Wih2  = (const float*)d_in[26];
  const float* Whh2  = (const float*)d_in[27];
  const float* bih2  = (const float*)d_in[28];
  const float* bhh2  = (const float*)d_in[29];
  const float* Wg1   = (const float*)d_in[30];
  const float* bg1   = (const float*)d_in[31];
  const float* gamma = (const float*)d_in[32];
  const float* beta  = (const float*)d_in[33];
  const float* Wg2   = (const float*)d_in[34];
  const float* bg2   = (const float*)d_in[35];

  float* ws  = (float*)d_ws;
  float* out = (float*)d_out;

  float* pwmF = ws + OFF_PWM_F;
  float* pwmB = ws + OFF_PWM_B;
  float* benF = ws + OFF_BEN_F;
  float* benB = ws + OFF_BEN_B;
  float* plat = ws + OFF_PLAT;
  float* p1i  = ws + OFF_P1I;
  float* p1h  = ws + OFF_P1H;
  float* p2i  = ws + OFF_P2I;
  float* p2h  = ws + OFF_P2H;
  float* wg1T = ws + OFF_WG1T;
  float* be1  = ws + OFF_BE1;
  float* be2  = ws + OFF_BE2;
  float* hf   = ws + OFF_HF;
  float* hb   = ws + OFF_HB;
  float* z    = ws + OFF_Z;
  float* h1w  = ws + OFF_H1;
  float* c1w  = ws + OFF_C1;
  float* h2w  = ws + OFF_H2;
  float* c2w  = ws + OFF_C2;
  float* dlq  = ws + OFF_DLQ;
  float* xbuf = ws + OFF_XBUF;
  float* muv  = ws + OFF_MU;
  float* rstdv= ws + OFF_RSTD;
  float* zw1  = ws + OFF_ZW1;

  PrepArgs pa;
  int ji = 0;
  auto JOB = [&](const float* a, const float* b, float* d, int p0, int p1, int p2, int p3, int m) {
    pa.j[ji].a = a; pa.j[ji].b = b; pa.j[ji].dst = d;
    pa.j[ji].p0 = p0; pa.j[ji].p1 = p1; pa.j[ji].p2 = p2; pa.j[ji].p3 = p3; pa.j[ji].mode = m; ++ji;
  };
  JOB(Wih_f, Whh_f, pwmF, 0,0,0,0, 4);
  JOB(Wih_b, Whh_b, pwmB, 0,0,0,0, 4);
  JOB(bih_f, bhh_f, benF, 0,0,0,0, 5);
  JOB(bih_b, bhh_b, benB, 0,0,0,0, 5);
  JOB(W_lat, nullptr, plat, 256, 256, 256, 2, 0);
  JOB(Wih1,  nullptr, p1i,  100, 279, 280, 4, 0);
  JOB(Whh1,  nullptr, p1h,  100, 100, 100, 4, 0);
  JOB(Wih2,  nullptr, p2i,  100, 100, 100, 4, 0);
  JOB(Whh2,  nullptr, p2h,  100, 100, 100, 4, 0);
  JOB(Wg1,   nullptr, wg1T, 25, 100, 100, 1, 0);
  JOB(bih1,  bhh1,  be1,  400, 0,0,0, 1);
  JOB(bih2,  bhh2,  be2,  400, 0,0,0, 1);

  prep_kernel<<<512, 256, 0, stream>>>(pa);

  enc_kernel<<<256, 512, 0, stream>>>(
      seq, seq_len, ymd, acq, Ea0, Ea1, Ea2, Es0, Es1, Es2,
      (const unsigned short*)pwmF, (const unsigned short*)pwmB,
      benF, benB, hf, hb);

  latent_kernel<<<256, 256, 0, stream>>>(
      hf, hb, (const float2*)plat, b_lat, z_noise, seq, seq_len,
      z, dlq, h1w, c1w, h2w, c2w);

  dec_zpre_kernel<<<256, 256, 0, stream>>>(z, (const float4*)p1i, zw1);

  for (int t = 0; t < 12; ++t) {
    dec_cell_kernel<<<256, 256, 0, stream>>>(
        zw1, dlq, macro, h1w, c1w, h2w, c2w,
        (const float4*)p1i, (const float4*)p1h, be1,
        (const float4*)p2i, (const float4*)p2h, be2, wg1T, bg1, xbuf, t);
    dec_stats_kernel<<<25, 256, 0, stream>>>(xbuf, muv, rstdv);
    dec_out_kernel<<<16, 256, 0, stream>>>(
        xbuf, muv, rstdv, gamma, beta, Wg2, bg2, dlq, out, t);
  }
}

// Round 21
// 3019.927 us; speedup vs baseline: 1.0452x; 1.0452x over previous
//
#include <hip/hip_runtime.h>
#include <math.h>

#define B_SZ   4096
#define T_SZ   60
#define F_SZ   30
#define H_ENC  256
#define HD_DEC 100
#define LATD   256
#define KM     352
#define KMP    360
#define NKK    11
#define DTAIL  24

enum {
  OFF_PWM_F = 0,
  OFF_PWM_B = OFF_PWM_F + 180224,
  OFF_BEN_F = OFF_PWM_B + 180224,
  OFF_BEN_B = OFF_BEN_F + 1024,
  OFF_PLAT  = OFF_BEN_B + 1024,
  OFF_P1I   = OFF_PLAT + 256*256*2,
  OFF_P1H   = OFF_P1I + 280*100*4,
  OFF_P2I   = OFF_P1H + 100*100*4,
  OFF_P2H   = OFF_P2I + 100*100*4,
  OFF_WG1T  = OFF_P2H + 100*100*4,
  OFF_BE1   = OFF_WG1T + 100*25,
  OFF_BE2   = OFF_BE1 + 400,
  OFF_HF    = OFF_BE2 + 400,
  OFF_HB    = OFF_HF + B_SZ*H_ENC,
  OFF_H1    = OFF_HB + B_SZ*H_ENC,
  OFF_C1    = OFF_H1 + B_SZ*HD_DEC,
  OFF_H2    = OFF_C1 + B_SZ*HD_DEC,
  OFF_C2    = OFF_H2 + B_SZ*HD_DEC,
  OFF_DLQ   = OFF_C2 + B_SZ*HD_DEC,
  OFF_XBUF  = OFF_DLQ + B_SZ*9,
  OFF_MU    = OFF_XBUF + B_SZ*25,
  OFF_RSTD  = OFF_MU + 25,
  OFF_ZW1   = OFF_RSTD + 25,
  WS_FLOATS = OFF_ZW1 + B_SZ*400
};

typedef __attribute__((ext_vector_type(8))) short short8v;
typedef __attribute__((ext_vector_type(4))) float f32x4;

__device__ __forceinline__ float sigf(float x) { return 1.0f / (1.0f + expf(-x)); }

__device__ __forceinline__ unsigned short f2bf(float f) {
  union { float f; unsigned int u; } v; v.f = f;
  unsigned int u = v.u + 0x7fffu + ((v.u >> 16) & 1u);
  return (unsigned short)(u >> 16);
}
__device__ __forceinline__ float bf2f(unsigned short s) {
  union { unsigned int u; float f; } v; v.u = ((unsigned int)s) << 16;
  return v.f;
}

// ---------------- prep ----------------
struct PJob { const float* a; const float* b; float* dst; int p0, p1, p2, p3, mode; };
struct PrepArgs { PJob j[12]; };

__device__ __forceinline__ float enc_wv(const float* wih, const float* whh, int k, int u, int g) {
  if (k < 74)  return wih[(g * 256 + u) * 74 + k];
  if (k < 76)  return 0.0f;
  if (k < 332) return whh[(g * 256 + u) * 256 + (k - 76)];
  return 0.0f;
}

__global__ __launch_bounds__(256) void prep_kernel(PrepArgs pa) {
  int gtid = blockIdx.x * blockDim.x + threadIdx.x;
  int stride = gridDim.x * blockDim.x;
  for (int jj = 0; jj < 12; ++jj) {
    PJob jb = pa.j[jj];
    if (jb.mode == 1) {
      for (int i = gtid; i < jb.p0; i += stride) jb.dst[i] = jb.a[i] + jb.b[i];
    } else if (jb.mode == 0) {
      int total = jb.p2 * jb.p0;
      for (int i = gtid; i < total; i += stride) {
        int k = i / jb.p0, u = i - k * jb.p0;
        float* d = jb.dst + (size_t)i * jb.p3;
        for (int g = 0; g < jb.p3; ++g)
          d[g] = (k < jb.p1) ? jb.a[(g * jb.p0 + u) * jb.p1 + k] : 0.0f;
      }
    } else if (jb.mode == 4) {
      int total = NKK * 64 * 64;
      for (int i = gtid; i < total; i += stride) {
        int kk = i / 4096, rem = i - kk * 4096;
        int ntg = rem >> 6, l = rem & 63;
        int n = ntg * 16 + (l & 15);
        int u = n >> 2, g = n & 3;
        int kb = kk * 32 + (l >> 4) * 8;
        unsigned int* d = (unsigned int*)jb.dst + (size_t)i * 4;
        for (int wd = 0; wd < 4; ++wd) {
          float lo = enc_wv(jb.a, jb.b, kb + 2 * wd,     u, g);
          float hi = enc_wv(jb.a, jb.b, kb + 2 * wd + 1, u, g);
          d[wd] = (unsigned int)f2bf(lo) | ((unsigned int)f2bf(hi) << 16);
        }
      }
    } else { // mode 5
      for (int i = gtid; i < 1024; i += stride) {
        int u = i >> 2, g = i & 3;
        jb.dst[i] = jb.a[g * 256 + u] + jb.b[g * 256 + u];
      }
    }
  }
}

#define GDOT(acc, c, w0, w1, w2, w3, xv) \
  acc = fmaf((w0).c, (xv).x, fmaf((w1).c, (xv).y, fmaf((w2).c, (xv).z, fmaf((w3).c, (xv).w, acc))))

// ---------------- encoder: r19 exactly (best verified: 2.49 ms) ----------------
__global__ __launch_bounds__(512) void enc_kernel(
    const float* __restrict__ seq, const int* __restrict__ seq_len,
    const int* __restrict__ ymd, const int* __restrict__ acq,
    const float* __restrict__ Ea0, const float* __restrict__ Ea1, const float* __restrict__ Ea2,
    const float* __restrict__ Es0, const float* __restrict__ Es1, const float* __restrict__ Es2,
    const unsigned short* __restrict__ PWMf, const unsigned short* __restrict__ PWMb,
    const float* __restrict__ benF, const float* __restrict__ benB,
    float* __restrict__ hf_out, float* __restrict__ hb_out)
{
  const int tid = threadIdx.x;
  const bool bwd = blockIdx.x >= 128;
  const int c = blockIdx.x & 127;
  const unsigned short* __restrict__ PWM = bwd ? PWMb : PWMf;
  const float* __restrict__ ben = bwd ? benB : benF;
  float* __restrict__ hout = bwd ? hb_out : hf_out;

  __shared__ __align__(16) unsigned short v_s[32][KMP];
  __shared__ float c_s[32][256];
  __shared__ int   len_s[32];

  for (int i = tid; i < 32 * KMP; i += 512) (&v_s[0][0])[i] = 0;
  for (int i = tid; i < 32 * 256; i += 512) (&c_s[0][0])[i] = 0.0f;
  if (tid < 32) len_s[tid] = seq_len[c + 128 * tid];
  __syncthreads();

  for (int i = tid; i < 32 * 28; i += 512) {
    int r = i / 28, d = i - r * 28;
    const int* aq = &acq[(c + 128 * r) * 3];
    float v;
    if (d < 16)      v = Ea0[aq[0] * 16 + d];
    else if (d < 24) v = Ea1[aq[1] * 8 + (d - 16)];
    else             v = Ea2[aq[2] * 4 + (d - 24)];
    v_s[r][30 + d] = f2bf(v);
  }

  const int w   = tid >> 6;
  const int l   = tid & 63;
  const int col = l & 15;
  const int qk  = l >> 4;
  const int g   = l & 3;
  const int usub = col >> 2;

  float bias_r[8];
  #pragma unroll
  for (int nt = 0; nt < 8; ++nt) bias_r[nt] = ben[128 * w + 16 * nt + col];

  __syncthreads();
  const int maxlen = len_s[0];

  for (int t = 0; t < maxlen; ++t) {
    for (int i = tid; i < 1472; i += 512) {
      if (i < 960) {
        int r = i / 30, k = i - r * 30;
        int len = len_s[r];
        int te = bwd ? max(len - 1 - t, 0) : t;
        v_s[r][k] = f2bf(seq[((size_t)(c + 128 * r) * T_SZ + te) * F_SZ + k]);
      } else {
        int ii = i - 960;
        int r = ii >> 4, d = ii & 15;
        int len = len_s[r];
        int te = bwd ? max(len - 1 - t, 0) : t;
        const int* ym = &ymd[((size_t)(c + 128 * r) * T_SZ + te) * 3];
        float v;
        if (d < 8)       v = Es0[ym[0] * 8 + d];
        else if (d < 12) v = Es1[ym[1] * 4 + (d - 8)];
        else             v = Es2[ym[2] * 4 + (d - 12)];
        v_s[r][58 + d] = f2bf(v);
      }
    }
    __syncthreads();

    f32x4 acc0[8], acc1[8];
    #pragma unroll
    for (int nt = 0; nt < 8; ++nt) {
      acc0[nt][0] = bias_r[nt]; acc0[nt][1] = bias_r[nt];
      acc0[nt][2] = bias_r[nt]; acc0[nt][3] = bias_r[nt];
      acc1[nt] = acc0[nt];
    }

    for (int kk = 0; kk < NKK; ++kk) {
      short8v a0 = *reinterpret_cast<const short8v*>(&v_s[col][32 * kk + 8 * qk]);
      short8v a1 = *reinterpret_cast<const short8v*>(&v_s[16 + col][32 * kk + 8 * qk]);
      const unsigned short* Bk = PWM + ((size_t)kk * 4096 + l) * 8;
      #pragma unroll
      for (int nt = 0; nt < 8; ++nt) {
        int ntg = 8 * w + nt;
        short8v b = *reinterpret_cast<const short8v*>(Bk + (size_t)ntg * 512);
        acc0[nt] = __builtin_amdgcn_mfma_f32_16x16x32_bf16(a0, b, acc0[nt], 0, 0, 0);
        acc1[nt] = __builtin_amdgcn_mfma_f32_16x16x32_bf16(a1, b, acc1[nt], 0, 0, 0);
      }
    }
    __syncthreads();

    #pragma unroll
    for (int rt = 0; rt < 2; ++rt) {
      #pragma unroll
      for (int nt = 0; nt < 8; ++nt) {
        int u = 32 * w + 4 * nt + usub;
        #pragma unroll
        for (int i = 0; i < 4; ++i) {
          int row = 16 * rt + qk * 4 + i;
          float val = rt == 0 ? acc0[nt][i] : acc1[nt][i];
          float act = (g == 2) ? tanhf(val) : sigf(val);
          float a1s = __shfl_xor(act, 1);
          float a2s = __shfl_xor(act, 2);
          float a3s = __shfl_xor(a1s, 2);
          if (g == 0 && t < len_s[row]) {
            float cc = c_s[row][u];
            float cn = a1s * cc + act * a2s;
            c_s[row][u] = cn;
            v_s[row][76 + u] = f2bf(a3s * tanhf(cn));
          }
        }
      }
    }
  }

  __syncthreads();
  for (int i = tid; i < 32 * 256; i += 512) {
    int r = i >> 8, u = i & 255;
    hout[(size_t)(c + 128 * r) * H_ENC + u] = bf2f(v_s[r][76 + u]);
  }
}

// ---------------- latent + fused z-precompute ----------------
__global__ __launch_bounds__(256) void latent_kernel(
    const float* __restrict__ hf, const float* __restrict__ hb,
    const float2* __restrict__ Plat, const float* __restrict__ b_lat,
    const float* __restrict__ z_noise, const float* __restrict__ seq,
    const int* __restrict__ seq_len, const float4* __restrict__ P1I,
    float* __restrict__ dlq, float* __restrict__ zw1,
    float* __restrict__ h1w, float* __restrict__ c1w,
    float* __restrict__ h2w, float* __restrict__ c2w)
{
  const int tid = threadIdx.x;
  const int b0 = blockIdx.x * 16;
  __shared__ float hs[16][H_ENC];
  for (int i = tid; i < 16 * H_ENC; i += 256)
    (&hs[0][0])[i] = hf[b0 * H_ENC + i] + hb[b0 * H_ENC + i];
  __syncthreads();

  const int u = tid;
  const float bm = b_lat[u], bv = b_lat[LATD + u];
  float am[16], av[16];
  #pragma unroll
  for (int r = 0; r < 16; ++r) { am[r] = bm; av[r] = bv; }

  for (int k = 0; k < H_ENC; k += 4) {
    const float2 p0 = Plat[(k + 0) * 256 + u];
    const float2 p1 = Plat[(k + 1) * 256 + u];
    const float2 p2 = Plat[(k + 2) * 256 + u];
    const float2 p3 = Plat[(k + 3) * 256 + u];
    #pragma unroll
    for (int r = 0; r < 16; ++r) {
      const float4 hv = *reinterpret_cast<const float4*>(&hs[r][k]);
      am[r] = fmaf(p0.x, hv.x, fmaf(p1.x, hv.y, fmaf(p2.x, hv.z, fmaf(p3.x, hv.w, am[r]))));
      av[r] = fmaf(p0.y, hv.x, fmaf(p1.y, hv.y, fmaf(p2.y, hv.z, fmaf(p3.y, hv.w, av[r]))));
    }
  }
  if (u < HD_DEC) {
    #pragma unroll
    for (int r = 0; r < 16; ++r) {
      int b = b0 + r;
      h1w[b * HD_DEC + u] = 0.0f; c1w[b * HD_DEC + u] = 0.0f;
      h2w[b * HD_DEC + u] = 0.0f; c2w[b * HD_DEC + u] = 0.0f;
    }
  }
  if (u < 9) {
    #pragma unroll
    for (int r = 0; r < 16; ++r) {
      int b = b0 + r;
      int len = seq_len[b];
      dlq[b * 9 + u] = seq[(b * T_SZ + (len - 1)) * F_SZ + 21 + u];
    }
  }
  __syncthreads();                  // hs reads done; reuse hs as z storage
  #pragma unroll
  for (int r = 0; r < 16; ++r) {
    int b = b0 + r;
    hs[r][u] = am[r] + sqrtf(expf(av[r])) * z_noise[b * LATD + u];
  }
  __syncthreads();                  // z ready in hs

  // fused zpre: zw1[b][400] = z @ Wih1[:, :256].T
  const int uu = tid & 127;
  const int grp = tid >> 7;
  const int r0 = grp * 8;
  if (uu < HD_DEC) {
    float a0[8], a1[8], a2[8], a3[8];
    #pragma unroll
    for (int r = 0; r < 8; ++r) { a0[r] = 0.0f; a1[r] = 0.0f; a2[r] = 0.0f; a3[r] = 0.0f; }
    for (int k = 0; k < LATD; k += 4) {
      const float4 w0 = P1I[(k + 0) * 100 + uu];
      const float4 w1 = P1I[(k + 1) * 100 + uu];
      const float4 w2 = P1I[(k + 2) * 100 + uu];
      const float4 w3 = P1I[(k + 3) * 100 + uu];
      #pragma unroll
      for (int r = 0; r < 8; ++r) {
        const float4 xv = *reinterpret_cast<const float4*>(&hs[r0 + r][k]);
        GDOT(a0[r], x, w0, w1, w2, w3, xv);
        GDOT(a1[r], y, w0, w1, w2, w3, xv);
        GDOT(a2[r], z, w0, w1, w2, w3, xv);
        GDOT(a3[r], w, w0, w1, w2, w3, xv);
      }
    }
    #pragma unroll
    for (int r = 0; r < 8; ++r) {
      int b = b0 + r0 + r;
      zw1[b * 400 + uu]       = a0[r];
      zw1[b * 400 + 100 + uu] = a1[r];
      zw1[b * 400 + 200 + uu] = a2[r];
      zw1[b * 400 + 300 + uu] = a3[r];
    }
  }
}

// ---------------- decoder cell step (fused BN+out of step t-1) ----------------
__global__ __launch_bounds__(256) void dec_cell_kernel(
    const float* __restrict__ zw1, const float* __restrict__ dlq0,
    const float* __restrict__ macro,
    float* __restrict__ h1w, float* __restrict__ c1w,
    float* __restrict__ h2w, float* __restrict__ c2w,
    const float4* __restrict__ P1I, const float4* __restrict__ P1H, const float* __restrict__ be1,
    const float4* __restrict__ P2I, const float4* __restrict__ P2H, const float* __restrict__ be2,
    const float* __restrict__ Wg1T, const float* __restrict__ bg1,
    const float* __restrict__ muv, const float* __restrict__ rstdv,
    const float* __restrict__ gamma, const float* __restrict__ beta,
    const float* __restrict__ Wg2, const float* __restrict__ bg2,
    float* __restrict__ xbuf, float* __restrict__ out, int t)
{
  const int tid = threadIdx.x;
  const int b0 = blockIdx.x * 16;
  __shared__ float di[16][DTAIL];
  __shared__ float xns[16][25];
  __shared__ float h1s[16][HD_DEC];
  __shared__ float h2s[16][HD_DEC];

  if (t > 0) {
    // BN + Wg2 for step t-1 using stats(t-1); fills di[.][0..9) and writes out
    for (int p = tid; p < 16 * 25; p += 256) {
      int r = p / 25, cc = p - r * 25;
      xns[r][cc] = gamma[cc] * (xbuf[(b0 + r) * 25 + cc] - muv[cc]) * rstdv[cc] + beta[cc];
    }
  } else {
    for (int p = tid; p < 16 * 9; p += 256) {
      int r = p / 9, j = p - r * 9;
      di[r][j] = dlq0[(b0 + r) * 9 + j];
    }
  }
  for (int i = tid; i < 16 * 15; i += 256) {   // macro + pad: di[.][9..24)
    int r = i / 15, k = i - r * 15;
    di[r][9 + k] = (k < 14) ? macro[((size_t)(b0 + r) * 12 + t) * 14 + k] : 0.0f;
  }
  for (int i = tid; i < 16 * HD_DEC; i += 256) {
    int r = i / HD_DEC, k = i - r * HD_DEC;
    h1s[r][k] = h1w[(b0 + r) * HD_DEC + k];
    h2s[r][k] = h2w[(b0 + r) * HD_DEC + k];
  }
  __syncthreads();
  if (t > 0) {
    for (int p = tid; p < 16 * 9; p += 256) {
      int r = p / 9, j = p - r * 9;
      float s = bg2[j];
      #pragma unroll
      for (int cc = 0; cc < 25; ++cc) s += xns[r][cc] * Wg2[j * 25 + cc];
      di[r][j] = s;
      out[(size_t)(b0 + r) * 108 + j * 12 + (t - 1)] = s;
    }
  }

  const int u = tid & 127;
  const int grp = tid >> 7;
  const int r0 = grp * 8;
  const bool act = u < HD_DEC;

  float c1r[8], c2r[8];
  if (act) {
    #pragma unroll
    for (int r = 0; r < 8; ++r) {
      c1r[r] = c1w[(b0 + r0 + r) * HD_DEC + u];
      c2r[r] = c2w[(b0 + r0 + r) * HD_DEC + u];
    }
  }
  __syncthreads();

  float a0[8], a1[8], a2[8], a3[8];
  if (act) {
    const float b0g = be1[u], b1g = be1[100 + u], b2g = be1[200 + u], b3g = be1[300 + u];
    #pragma unroll
    for (int r = 0; r < 8; ++r) {
      const float* zw = &zw1[(size_t)(b0 + r0 + r) * 400];
      a0[r] = b0g + zw[u];
      a1[r] = b1g + zw[100 + u];
      a2[r] = b2g + zw[200 + u];
      a3[r] = b3g + zw[300 + u];
    }
    for (int k = 0; k < DTAIL; k += 4) {
      const int kk = LATD + k;
      const float4 w0 = P1I[(kk + 0) * 100 + u];
      const float4 w1 = P1I[(kk + 1) * 100 + u];
      const float4 w2 = P1I[(kk + 2) * 100 + u];
      const float4 w3 = P1I[(kk + 3) * 100 + u];
      #pragma unroll
      for (int r = 0; r < 8; ++r) {
        const float4 xv = *reinterpret_cast<const float4*>(&di[r0 + r][k]);
        GDOT(a0[r], x, w0, w1, w2, w3, xv);
        GDOT(a1[r], y, w0, w1, w2, w3, xv);
        GDOT(a2[r], z, w0, w1, w2, w3, xv);
        GDOT(a3[r], w, w0, w1, w2, w3, xv);
      }
    }
    for (int k = 0; k < HD_DEC; k += 4) {
      const float4 w0 = P1H[(k + 0) * 100 + u];
      const float4 w1 = P1H[(k + 1) * 100 + u];
      const float4 w2 = P1H[(k + 2) * 100 + u];
      const float4 w3 = P1H[(k + 3) * 100 + u];
      #pragma unroll
      for (int r = 0; r < 8; ++r) {
        const float4 hv = *reinterpret_cast<const float4*>(&h1s[r0 + r][k]);
        GDOT(a0[r], x, w0, w1, w2, w3, hv);
        GDOT(a1[r], y, w0, w1, w2, w3, hv);
        GDOT(a2[r], z, w0, w1, w2, w3, hv);
        GDOT(a3[r], w, w0, w1, w2, w3, hv);
      }
    }
  }
  __syncthreads();
  if (act) {
    #pragma unroll
    for (int r = 0; r < 8; ++r) {
      float ig = sigf(a0[r]), fg = sigf(a1[r]), gg = tanhf(a2[r]), og = sigf(a3[r]);
      float cn = fg * c1r[r] + ig * gg;
      float hn = og * tanhf(cn);
      int b = b0 + r0 + r;
      h1s[r0 + r][u] = hn;
      h1w[b * HD_DEC + u] = hn;
      c1w[b * HD_DEC + u] = cn;
    }
  }
  __syncthreads();

  if (act) {
    const float b0g = be2[u], b1g = be2[100 + u], b2g = be2[200 + u], b3g = be2[300 + u];
    #pragma unroll
    for (int r = 0; r < 8; ++r) { a0[r] = b0g; a1[r] = b1g; a2[r] = b2g; a3[r] = b3g; }
    for (int k = 0; k < HD_DEC; k += 4) {
      const float4 w0 = P2I[(k + 0) * 100 + u];
      const float4 w1 = P2I[(k + 1) * 100 + u];
      const float4 w2 = P2I[(k + 2) * 100 + u];
      const float4 w3 = P2I[(k + 3) * 100 + u];
      #pragma unroll
      for (int r = 0; r < 8; ++r) {
        const float4 hv = *reinterpret_cast<const float4*>(&h1s[r0 + r][k]);
        GDOT(a0[r], x, w0, w1, w2, w3, hv);
        GDOT(a1[r], y, w0, w1, w2, w3, hv);
        GDOT(a2[r], z, w0, w1, w2, w3, hv);
        GDOT(a3[r], w, w0, w1, w2, w3, hv);
      }
    }
    for (int k = 0; k < HD_DEC; k += 4) {
      const float4 w0 = P2H[(k + 0) * 100 + u];
      const float4 w1 = P2H[(k + 1) * 100 + u];
      const float4 w2 = P2H[(k + 2) * 100 + u];
      const float4 w3 = P2H[(k + 3) * 100 + u];
      #pragma unroll
      for (int r = 0; r < 8; ++r) {
        const float4 hv = *reinterpret_cast<const float4*>(&h2s[r0 + r][k]);
        GDOT(a0[r], x, w0, w1, w2, w3, hv);
        GDOT(a1[r], y, w0, w1, w2, w3, hv);
        GDOT(a2[r], z, w0, w1, w2, w3, hv);
        GDOT(a3[r], w, w0, w1, w2, w3, hv);
      }
    }
  }
  __syncthreads();
  if (act) {
    #pragma unroll
    for (int r = 0; r < 8; ++r) {
      float ig = sigf(a0[r]), fg = sigf(a1[r]), gg = tanhf(a2[r]), og = sigf(a3[r]);
      float cn = fg * c2r[r] + ig * gg;
      float hn = og * tanhf(cn);
      int b = b0 + r0 + r;
      h2s[r0 + r][u] = hn;
      h2w[b * HD_DEC + u] = hn;
      c2w[b * HD_DEC + u] = cn;
    }
  }
  __syncthreads();

  for (int p = tid; p < 16 * 25; p += 256) {
    int r = p / 25, cc = p - r * 25;
    float s = bg1[cc];
    for (int k = 0; k < HD_DEC; k += 4) {
      const float4 hv = *reinterpret_cast<const float4*>(&h2s[r][k]);
      s += hv.x * Wg1T[k * 25 + cc] + hv.y * Wg1T[(k + 1) * 25 + cc]
         + hv.z * Wg1T[(k + 2) * 25 + cc] + hv.w * Wg1T[(k + 3) * 25 + cc];
    }
    xbuf[(b0 + r) * 25 + cc] = fmaxf(s, 0.0f);
  }
}

// ---------------- decoder batchnorm stats ----------------
__global__ __launch_bounds__(256) void dec_stats_kernel(
    const float* __restrict__ xbuf, float* __restrict__ muv, float* __restrict__ rstdv)
{
  const int col = blockIdx.x;
  const int tid = threadIdx.x;
  __shared__ float red[256];
  float v[16];
  float s = 0.0f;
  #pragma unroll
  for (int i = 0; i < 16; ++i) { v[i] = xbuf[(tid + 256 * i) * 25 + col]; s += v[i]; }
  red[tid] = s; __syncthreads();
  for (int off = 128; off >= 1; off >>= 1) {
    if (tid < off) red[tid] += red[tid + off];
    __syncthreads();
  }
  float mean = red[0] / (float)B_SZ;
  __syncthreads();
  float s2 = 0.0f;
  #pragma unroll
  for (int i = 0; i < 16; ++i) { float d = v[i] - mean; s2 += d * d; }
  red[tid] = s2; __syncthreads();
  for (int off = 128; off >= 1; off >>= 1) {
    if (tid < off) red[tid] += red[tid + off];
    __syncthreads();
  }
  if (tid == 0) {
    muv[col] = mean;
    rstdv[col] = rsqrtf(red[0] / (float)B_SZ + 1e-5f);
  }
}

// ---------------- final out (t = 11) ----------------
__global__ __launch_bounds__(256) void dec_finalout_kernel(
    const float* __restrict__ xbuf, const float* __restrict__ muv, const float* __restrict__ rstdv,
    const float* __restrict__ gamma, const float* __restrict__ beta,
    const float* __restrict__ Wg2, const float* __restrict__ bg2,
    float* __restrict__ out)
{
  int b = blockIdx.x * 256 + threadIdx.x;
  float xn[25];
  #pragma unroll
  for (int c = 0; c < 25; ++c)
    xn[c] = gamma[c] * (xbuf[b * 25 + c] - muv[c]) * rstdv[c] + beta[c];
  #pragma unroll
  for (int j = 0; j < 9; ++j) {
    float s = bg2[j];
    #pragma unroll
    for (int c = 0; c < 25; ++c) s += xn[c] * Wg2[j * 25 + c];
    out[(size_t)b * 108 + j * 12 + 11] = s;
  }
}

// ---------------- host launch ----------------
extern "C" void kernel_launch(void* const* d_in, const int* in_sizes, int n_in,
                              void* d_out, int out_size, void* d_ws, size_t ws_size,
                              hipStream_t stream)
{
  const float* seq     = (const float*)d_in[0];
  const int*   seq_len = (const int*)  d_in[1];
  const int*   ymd     = (const int*)  d_in[2];
  const int*   acq     = (const int*)  d_in[3];
  const float* macro   = (const float*)d_in[4];
  const float* z_noise = (const float*)d_in[5];
  const float* Ea0 = (const float*)d_in[6];
  const float* Ea1 = (const float*)d_in[7];
  const float* Ea2 = (const float*)d_in[8];
  const float* Es0 = (const float*)d_in[9];
  const float* Es1 = (const float*)d_in[10];
  const float* Es2 = (const float*)d_in[11];
  const float* Wih_f = (const float*)d_in[12];
  const float* Whh_f = (const float*)d_in[13];
  const float* bih_f = (const float*)d_in[14];
  const float* bhh_f = (const float*)d_in[15];
  const float* Wih_b = (const float*)d_in[16];
  const float* Whh_b = (const float*)d_in[17];
  const float* bih_b = (const float*)d_in[18];
  const float* bhh_b = (const float*)d_in[19];
  const float* W_lat = (const float*)d_in[20];
  const float* b_lat = (const float*)d_in[21];
  const float* Wih1  = (const float*)d_in[22];
  const float* Whh1  = (const float*)d_in[23];
  const float* bih1  = (const float*)d_in[24];
  const float* bhh1  = (const float*)d_in[25];
  const float* Wih2  = (const float*)d_in[26];
  const float* Whh2  = (const float*)d_in[27];
  const float* bih2  = (const float*)d_in[28];
  const float* bhh2  = (const float*)d_in[29];
  const float* Wg1   = (const float*)d_in[30];
  const float* bg1   = (const float*)d_in[31];
  const float* gamma = (const float*)d_in[32];
  const float* beta  = (const float*)d_in[33];
  const float* Wg2   = (const float*)d_in[34];
  const float* bg2   = (const float*)d_in[35];

  float* ws  = (float*)d_ws;
  float* out = (float*)d_out;

  float* pwmF = ws + OFF_PWM_F;
  float* pwmB = ws + OFF_PWM_B;
  float* benF = ws + OFF_BEN_F;
  float* benB = ws + OFF_BEN_B;
  float* plat = ws + OFF_PLAT;
  float* p1i  = ws + OFF_P1I;
  float* p1h  = ws + OFF_P1H;
  float* p2i  = ws + OFF_P2I;
  float* p2h  = ws + OFF_P2H;
  float* wg1T = ws + OFF_WG1T;
  float* be1  = ws + OFF_BE1;
  float* be2  = ws + OFF_BE2;
  float* hf   = ws + OFF_HF;
  float* hb   = ws + OFF_HB;
  float* h1w  = ws + OFF_H1;
  float* c1w  = ws + OFF_C1;
  float* h2w  = ws + OFF_H2;
  float* c2w  = ws + OFF_C2;
  float* dlq  = ws + OFF_DLQ;
  float* xbuf = ws + OFF_XBUF;
  float* muv  = ws + OFF_MU;
  float* rstdv= ws + OFF_RSTD;
  float* zw1  = ws + OFF_ZW1;

  PrepArgs pa;
  int ji = 0;
  auto JOB = [&](const float* a, const float* b, float* d, int p0, int p1, int p2, int p3, int m) {
    pa.j[ji].a = a; pa.j[ji].b = b; pa.j[ji].dst = d;
    pa.j[ji].p0 = p0; pa.j[ji].p1 = p1; pa.j[ji].p2 = p2; pa.j[ji].p3 = p3; pa.j[ji].mode = m; ++ji;
  };
  JOB(Wih_f, Whh_f, pwmF, 0,0,0,0, 4);
  JOB(Wih_b, Whh_b, pwmB, 0,0,0,0, 4);
  JOB(bih_f, bhh_f, benF, 0,0,0,0, 5);
  JOB(bih_b, bhh_b, benB, 0,0,0,0, 5);
  JOB(W_lat, nullptr, plat, 256, 256, 256, 2, 0);
  JOB(Wih1,  nullptr, p1i,  100, 279, 280, 4, 0);
  JOB(Whh1,  nullptr, p1h,  100, 100, 100, 4, 0);
  JOB(Wih2,  nullptr, p2i,  100, 100, 100, 4, 0);
  JOB(Whh2,  nullptr, p2h,  100, 100, 100, 4, 0);
  JOB(Wg1,   nullptr, wg1T, 25, 100, 100, 1, 0);
  JOB(bih1,  bhh1,  be1,  400, 0,0,0, 1);
  JOB(bih2,  bhh2,  be2,  400, 0,0,0, 1);

  prep_kernel<<<512, 256, 0, stream>>>(pa);

  enc_kernel<<<256, 512, 0, stream>>>(
      seq, seq_len, ymd, acq, Ea0, Ea1, Ea2, Es0, Es1, Es2,
      (const unsigned short*)pwmF, (const unsigned short*)pwmB,
      benF, benB, hf, hb);

  latent_kernel<<<256, 256, 0, stream>>>(
      hf, hb, (const float2*)plat, b_lat, z_noise, seq, seq_len,
      (const float4*)p1i, dlq, zw1, h1w, c1w, h2w, c2w);

  for (int t = 0; t < 12; ++t) {
    dec_cell_kernel<<<256, 256, 0, stream>>>(
        zw1, dlq, macro, h1w, c1w, h2w, c2w,
        (const float4*)p1i, (const float4*)p1h, be1,
        (const float4*)p2i, (const float4*)p2h, be2, wg1T, bg1,
        muv, rstdv, gamma, beta, Wg2, bg2, xbuf, out, t);
    dec_stats_kernel<<<25, 256, 0, stream>>>(xbuf, muv, rstdv);
  }
  dec_finalout_kernel<<<16, 256, 0, stream>>>(
      xbuf, muv, rstdv, gamma, beta, Wg2, bg2, out);
}